// Round 9
// baseline (1705.619 us; speedup 1.0000x reference)
//
#include <hip/hip_runtime.h>

// Problem constants
#define SEQ 512
#define HID 400
#define GATES 1600   // 4*HID
#define E1 800       // 2*HID
#define TEAM 25      // workgroups per direction in the recurrence
#define RECGRID 256  // candidate WGs launched for team formation (32/XCD)
#define ROWS 64      // gate rows per WG   = GATES/TEAM
#define HSL 16       // h values per WG    = HID/TEAM

__device__ __forceinline__ float bf2f(unsigned short u) {
    return __uint_as_float(((unsigned)u) << 16);
}
__device__ __forceinline__ unsigned short f2bf(float f) {
    unsigned u = __float_as_uint(f);
    u += 0x7FFFu + ((u >> 16) & 1u);   // RNE
    return (unsigned short)(u >> 16);
}
__device__ __forceinline__ float sigm(float x) { return 1.f / (1.f + __expf(-x)); }
__device__ __forceinline__ float tanh_f(float x) {
    float xc = fminf(fmaxf(x, -15.f), 15.f);
    float e = __expf(2.f * xc);
    return (e - 1.f) / (e + 1.f);
}
__device__ __forceinline__ float loadx(const void* p, size_t i, int isbf) {
    return isbf ? bf2f(((const unsigned short*)p)[i]) : ((const float*)p)[i];
}

// R1-style tag poll with hedge: proven MALL exchange loop (do not restructure;
// R2/R4/R6/R7 all showed any variation regresses).
__device__ __forceinline__ unsigned long long poll_tag(
        const unsigned long long* hx, const unsigned long long* hx2,
        size_t eidx, unsigned want) {
    const volatile unsigned long long* p =
        (const volatile unsigned long long*)&hx[eidx];
    unsigned long long w;
    int spin = 0;
    for (;;) {
        w = *p;
        if ((unsigned)(w >> 32) == want) break;
        if (++spin >= 24) {
            w = __hip_atomic_load(&hx2[eidx], __ATOMIC_RELAXED,
                                  __HIP_MEMORY_SCOPE_AGENT);
            if ((unsigned)(w >> 32) == want) break;
            spin = 0;
        }
    }
    return w;
}

// ------------------------------------------------- embedding (+fused detect)
// Each block self-detects dtype from the same 2048 samples the old
// detect_kernel used; block 0 also publishes dtf and zeroes the sync areas.
// Removes one dispatch (~25us launch gap).
__global__ void embed_kernel(const int* __restrict__ words, const int* __restrict__ tags,
                             const void* __restrict__ wemb, const void* __restrict__ temb,
                             float* __restrict__ x /* [SEQ][400] f32 */,
                             unsigned* __restrict__ dtf,
                             unsigned* __restrict__ syncz /* 128B to zero */) {
    __shared__ int cnt;
    int tid = threadIdx.x;                 // 128 threads
    int t = blockIdx.x;
    if (tid == 0) cnt = 0;
    __syncthreads();
    const unsigned short* wh = (const unsigned short*)wemb;
    int pass = 0;
    for (int i = 0; i < 16; ++i) {         // 128*16 = same 2048-sample set
        unsigned short u = wh[tid * 16 + i];
        int e = (u >> 7) & 0xFF;
        pass += (e >= 100 && e <= 130) ? 1 : 0;
    }
    atomicAdd(&cnt, pass);
    __syncthreads();
    int isbf = (cnt >= 1843) ? 1 : 0;      // 90% of 2048
    if (t == 0) {
        if (tid < 32) syncz[tid] = 0u;
        if (tid == 0) *dtf = (unsigned)isbf;
    }
    int w = words[t], g = tags[t];
    for (int k = tid; k < HID; k += blockDim.x) {
        float v = (k < 300) ? loadx(wemb, (size_t)w * 300 + k, isbf)
                            : loadx(temb, (size_t)g * 100 + (k - 300), isbf);
        x[(size_t)t * HID + k] = v;
    }
}

// ---------------------------------------------------------- input projection
// (now used for layer 0 only; layer 1's projection runs as helper work inside
// rec_kernel's unclaimed WGs). Unchanged code.
__global__ __launch_bounds__(256) void proj_kernel(
        const void* __restrict__ Araw, int tagged,
        const void* __restrict__ Wraw /* [2][GATES][K] */,
        const void* __restrict__ bihRaw, const void* __restrict__ bhhRaw,
        float* __restrict__ xi /* [2][SEQ][GATES] */,
        int K, const unsigned* __restrict__ dtf) {
    const int isbf = (int)*dtf;
    __shared__ float As[16][132];
    __shared__ float Ws[16][68];
    int tid = threadIdx.x;
    int t0 = blockIdx.x * 128, n0 = blockIdx.y * 64, dir = blockIdx.z;
    int arow = tid >> 1, akoff = (tid & 1) * 8;
    int wrow = tid >> 2, wkoff = (tid & 3) * 4;
    int tx = (tid & 15) * 4;        // n-offset 0..63
    int ty = (tid >> 4) * 8;        // t-offset 0..127

    const float* Af = (const float*)Araw + (size_t)(t0 + arow) * K + akoff;
    const unsigned long long* At = (const unsigned long long*)Araw +
                                   (size_t)(t0 + arow) * K + akoff;
    size_t wbase = (size_t)(dir * GATES + n0 + wrow) * K + wkoff;
    const float* Wf = (const float*)Wraw + wbase;
    const unsigned short* Wh = (const unsigned short*)Wraw + wbase;

    float acc[8][4] = {};
    for (int k0 = 0; k0 < K; k0 += 16) {
        float av8[8];
        if (tagged) {
            ulonglong2 q0 = *(const ulonglong2*)(At + k0);
            ulonglong2 q1 = *(const ulonglong2*)(At + k0 + 2);
            ulonglong2 q2 = *(const ulonglong2*)(At + k0 + 4);
            ulonglong2 q3 = *(const ulonglong2*)(At + k0 + 6);
            av8[0] = __uint_as_float((unsigned)q0.x); av8[1] = __uint_as_float((unsigned)q0.y);
            av8[2] = __uint_as_float((unsigned)q1.x); av8[3] = __uint_as_float((unsigned)q1.y);
            av8[4] = __uint_as_float((unsigned)q2.x); av8[5] = __uint_as_float((unsigned)q2.y);
            av8[6] = __uint_as_float((unsigned)q3.x); av8[7] = __uint_as_float((unsigned)q3.y);
        } else {
            float4 a0 = *(const float4*)(Af + k0);
            float4 a1 = *(const float4*)(Af + k0 + 4);
            av8[0] = a0.x; av8[1] = a0.y; av8[2] = a0.z; av8[3] = a0.w;
            av8[4] = a1.x; av8[5] = a1.y; av8[6] = a1.z; av8[7] = a1.w;
        }
        float4 wv;
        if (isbf) {
            ushort4 w4 = *(const ushort4*)(Wh + k0);
            wv = make_float4(bf2f(w4.x), bf2f(w4.y), bf2f(w4.z), bf2f(w4.w));
        } else {
            wv = *(const float4*)(Wf + k0);
        }
        __syncthreads();
#pragma unroll
        for (int i = 0; i < 8; ++i) As[akoff + i][arow] = av8[i];
        Ws[wkoff + 0][wrow] = wv.x; Ws[wkoff + 1][wrow] = wv.y;
        Ws[wkoff + 2][wrow] = wv.z; Ws[wkoff + 3][wrow] = wv.w;
        __syncthreads();
#pragma unroll
        for (int kk = 0; kk < 16; ++kk) {
            float4 alo = *(const float4*)&As[kk][ty];
            float4 ahi = *(const float4*)&As[kk][ty + 4];
            float4 w4  = *(const float4*)&Ws[kk][tx];
            float av[8] = {alo.x, alo.y, alo.z, alo.w, ahi.x, ahi.y, ahi.z, ahi.w};
            float wvv[4] = {w4.x, w4.y, w4.z, w4.w};
#pragma unroll
            for (int i = 0; i < 8; ++i)
#pragma unroll
                for (int j = 0; j < 4; ++j)
                    acc[i][j] = fmaf(av[i], wvv[j], acc[i][j]);
        }
    }
    float bias[4];
#pragma unroll
    for (int j = 0; j < 4; ++j) {
        int n = n0 + tx + j;
        bias[j] = loadx(bihRaw, dir * GATES + n, isbf) + loadx(bhhRaw, dir * GATES + n, isbf);
    }
    float* xout = xi + (size_t)dir * SEQ * GATES;
#pragma unroll
    for (int i = 0; i < 8; ++i) {
        int t = t0 + ty + i;
        float4 o = make_float4(acc[i][0] + bias[0], acc[i][1] + bias[1],
                               acc[i][2] + bias[2], acc[i][3] + bias[3]);
        *(float4*)&xout[(size_t)t * GATES + n0 + tx] = o;
    }
}

// ------------------------------------------------------------- LSTM recurrence
// ROUND-13. The rec-TEAM path is frozen at the R5 configuration (713us; every
// poll-path variation R2/R4/R6/R7 regressed -- see R12 scoreboard comment).
// NEW: the 206 unclaimed WGs no longer exit. They run helper jobs that
// previously cost separate dispatches (~25us launch gap each):
//   mode 0 (layer-0 dispatch): compute layer-1's input projection xi1 tile by
//     tile. Safety: a tile [t0,t0+128) is processed only after BOTH sentinel
//     tags (fwd row t0+127, bwd row t0) match -- at that point (a) all tile
//     inputs are causally published, and (b) the fwd/bwd teams have already
//     CONSUMED xi[*][tile rows] (they read xi[t] at the step that publishes
//     h[t]), so overwriting xi in place is race-free. A-loads are volatile +
//     per-element tag-verified (hedged). Same k-ascending fmaf order as
//     proj_kernel -> xi bitwise identical.
//   mode 1 (layer-1 dispatch): compute st (sv/tv) one row per wave, after a
//     lane-0 sentinel poll; exact st_kernel lane-stride + butterfly order ->
//     sv/tv bitwise identical.
// Steady-state extra MALL pressure: ~200 sentinel-polling lanes vs 20000
// existing poll lanes (~+1%) -- below the R6/R7 contention regime.
struct SyncArea { unsigned cnt[8]; unsigned claim[2]; unsigned pad[6]; };

__global__ __launch_bounds__(512, 2) void rec_kernel(
        const float* __restrict__ xi /* [2][SEQ][GATES] */,
        const void* __restrict__ whhRaw /* [2][GATES][HID] */,
        unsigned long long* __restrict__ hx  /* [SEQ][E1] tagged, volatile path */,
        unsigned long long* __restrict__ hx2 /* [SEQ][E1] tagged, MALL backup */,
        unsigned tagbase, SyncArea* __restrict__ sy,
        const unsigned* __restrict__ dtf,
        int mode,
        const void* __restrict__ wih1, const void* __restrict__ bih1,
        const void* __restrict__ bhh1, float* __restrict__ xiOut,
        const void* __restrict__ fw, float* __restrict__ sv,
        float* __restrict__ tv) {
    int tid = threadIdx.x;
    __shared__ int role[2];   // [0]=dir (0/1/2=helper), [1]=wg rank
    if (tid == 0) {
        unsigned xcd = __builtin_amdgcn_s_getreg((3 << 11) | 20) & 0xFu; // HW_REG_XCC_ID
        unsigned rank = atomicAdd(&sy->cnt[xcd], 1u);
        unsigned group = rank / TEAM;
        unsigned key = 1u + xcd * 64u + group;
        if ((rank % TEAM) == TEAM - 1) {          // group leader: claim a direction
            unsigned prev = atomicCAS(&sy->claim[0], 0u, key);
            if (prev != 0u) atomicCAS(&sy->claim[1], 0u, key);
        }
        int dir = -1;
        while (dir < 0) {
            unsigned c0 = __hip_atomic_load(&sy->claim[0], __ATOMIC_RELAXED,
                                            __HIP_MEMORY_SCOPE_AGENT);
            unsigned c1 = __hip_atomic_load(&sy->claim[1], __ATOMIC_RELAXED,
                                            __HIP_MEMORY_SCOPE_AGENT);
            if (c0 == key) dir = 0;
            else if (c1 == key) dir = 1;
            else if (c0 != 0u && c1 != 0u) dir = 2;
        }
        role[0] = dir;
        role[1] = (int)(rank % TEAM);
    }
    __syncthreads();
    const int dir = role[0];
    const int wg  = role[1];

    __shared__ __align__(16) float hbuf[16 * 28];        // stride-28 padded
    __shared__ __align__(16) float partials[ROWS][20];   // 16 cols used, 20 for align
    __shared__ __align__(16) float gates[ROWS];
    // helper-only staging (raises LDS to ~20.5KB; still 2 WGs/CU per launch_bounds)
    __shared__ __align__(16) float As2[16][132];
    __shared__ __align__(16) float Ws2[16][68];
    __shared__ int hticket;

    if (dir == 2) {
        // ======================= HELPER PATH (unclaimed WGs) =================
        const int isbf = (int)*dtf;
        if (mode == 0) {
            // ---- layer-1 input projection: 200 tiles of 128x64
            for (;;) {
                if (tid == 0) hticket = (int)atomicAdd(&sy->pad[0], 1u);
                __syncthreads();
                int tk = hticket;
                if (tk >= 200) return;
                int t0 = (tk & 3) * 128;
                int n0 = ((tk >> 2) % 25) * 64;
                int dw = tk / 100;
                // sentinels: fwd row t0+127 (tag t0+128), bwd row t0 (tag 512-t0)
                if (tid == 0)
                    (void)poll_tag(hx, hx2, (size_t)(t0 + 127) * E1 + 0,
                                   (unsigned)(t0 + 128));
                if (tid == 1)
                    (void)poll_tag(hx, hx2, (size_t)t0 * E1 + HID,
                                   (unsigned)(512 - t0));
                __syncthreads();

                float acc[4][4] = {};
                int arow = tid >> 2, akoff = (tid & 3) * 4;   // A stage: 4 elems
                int wrow = tid >> 3, wkoff = (tid & 7) * 2;   // W stage: 2 elems
                int tx = (tid & 15) * 4, ty = (tid >> 4) * 4; // 4x4 micro-acc
                int tA = t0 + arow;
                for (int k0 = 0; k0 < E1; k0 += 16) {
                    float a4[4];
#pragma unroll
                    for (int j = 0; j < 4; ++j) {
                        int e = k0 + akoff + j;
                        unsigned want = (e < HID) ? (unsigned)(tA + 1)
                                                  : (unsigned)(512 - tA);
                        unsigned long long w =
                            poll_tag(hx, hx2, (size_t)tA * E1 + e, want);
                        a4[j] = __uint_as_float((unsigned)w);
                    }
                    float wf0 = loadx(wih1, ((size_t)(dw * GATES + n0 + wrow)) * E1
                                            + k0 + wkoff + 0, isbf);
                    float wf1 = loadx(wih1, ((size_t)(dw * GATES + n0 + wrow)) * E1
                                            + k0 + wkoff + 1, isbf);
                    __syncthreads();
#pragma unroll
                    for (int j = 0; j < 4; ++j) As2[akoff + j][arow] = a4[j];
                    Ws2[wkoff + 0][wrow] = wf0;
                    Ws2[wkoff + 1][wrow] = wf1;
                    __syncthreads();
#pragma unroll
                    for (int kk = 0; kk < 16; ++kk) {
                        float4 av = *(const float4*)&As2[kk][ty];
                        float4 w4 = *(const float4*)&Ws2[kk][tx];
                        float avv[4] = {av.x, av.y, av.z, av.w};
                        float wvv[4] = {w4.x, w4.y, w4.z, w4.w};
#pragma unroll
                        for (int i = 0; i < 4; ++i)
#pragma unroll
                            for (int j = 0; j < 4; ++j)
                                acc[i][j] = fmaf(avv[i], wvv[j], acc[i][j]);
                    }
                }
                float bias[4];
#pragma unroll
                for (int j = 0; j < 4; ++j) {
                    int n = n0 + tx + j;
                    bias[j] = loadx(bih1, dw * GATES + n, isbf)
                            + loadx(bhh1, dw * GATES + n, isbf);
                }
                float* xo = xiOut + (size_t)dw * SEQ * GATES;
#pragma unroll
                for (int i = 0; i < 4; ++i) {
                    int t = t0 + ty + i;
                    float4 o = make_float4(acc[i][0] + bias[0], acc[i][1] + bias[1],
                                           acc[i][2] + bias[2], acc[i][3] + bias[3]);
                    *(float4*)&xo[(size_t)t * GATES + n0 + tx] = o;
                }
                __syncthreads();   // protect LDS before next ticket
            }
        } else {
            // ---- st: 64 chunks x 8 rows, one row per wave, exact st order
            int wid = tid >> 6, lane = tid & 63;
            for (;;) {
                if (tid == 0) hticket = (int)atomicAdd(&sy->pad[0], 1u);
                __syncthreads();
                int ck = hticket;
                if (ck >= 64) return;
                int i = ck * 8 + wid;
                // sentinels for row i (layer-1 tags: fwd 513+i, bwd 1024-i)
                if (lane == 0) {
                    (void)poll_tag(hx, hx2, (size_t)i * E1 + 0, (unsigned)(513 + i));
                    (void)poll_tag(hx, hx2, (size_t)i * E1 + HID, (unsigned)(1024 - i));
                }
                float s = 0.f, t2 = 0.f;
                for (int j = lane; j < E1; j += 64) {
                    unsigned want = (j < HID) ? (unsigned)(513 + i)
                                              : (unsigned)(1024 - i);
                    unsigned long long w = poll_tag(hx, hx2, (size_t)i * E1 + j, want);
                    float hv = __uint_as_float((unsigned)w);
                    s  += hv * loadx(fw, j, isbf);
                    t2 += hv * loadx(fw, E1 + j, isbf);
                }
#pragma unroll
                for (int o = 32; o > 0; o >>= 1) {
                    s  += __shfl_xor(s, o, 64);
                    t2 += __shfl_xor(t2, o, 64);
                }
                if (lane == 0) { sv[i] = s; tv[i] = t2; }
                __syncthreads();   // rejoin waves before next ticket
            }
        }
    }
    // ========================== REC-TEAM PATH (frozen R5) ====================
    const int chunk = tid & 15;    // 0..15 -> cols chunk*25..+24
    const int rg    = tid >> 4;    // 0..31 -> rows rg*2..+1
    const int isbf  = (int)*dtf;
    const int dirHID = dir * HID;

    // ---- load this lane's weight tile: 2 rows x 25 cols, REGISTER-resident
    float wv[2][25];
#pragma unroll
    for (int r = 0; r < 2; ++r) {
        int lr = rg * 2 + r;                // local row 0..63
        int jj = lr >> 2, gg = lr & 3;      // h index, gate (i,f,g,o)
        int grow = gg * HID + wg * HSL + jj; // global gate row
        size_t base = ((size_t)dir * GATES + grow) * HID + chunk * 25;
        if (isbf) {
            const unsigned short* p = (const unsigned short*)whhRaw + base;
#pragma unroll
            for (int c = 0; c < 25; ++c) wv[r][c] = bf2f(p[c]);
        } else {
            const float* p = (const float*)whhRaw + base;
#pragma unroll
            for (int c = 0; c < 25; ++c) wv[r][c] = p[c];
        }
    }

    int xrow = 0;
    if (tid < ROWS) { int jj = tid >> 2, gg = tid & 3; xrow = gg * HID + wg * HSL + jj; }
    const int hIdx = (tid / 25) * 28 + (tid % 25);   // padded scatter slot (tid<HID)
    const float* xibase = xi + (size_t)dir * SEQ * GATES;
    // wave-7 publisher lanes (tid 448..463): they never poll (poll set tid<400)
    const int pl = tid - 448;                // publisher lane 0..15 when valid
    float cstate = 0.f;                      // lane pl<16 owns c for h-idx wg*HSL+pl
    size_t myelem = dirHID + wg * HSL + (pl & 15);

#pragma unroll 1
    for (int k = 0; k < SEQ; ++k) {
        int t = dir ? (SEQ - 1 - k) : k;
        float xiv = 0.f;
        if (tid < ROWS) xiv = xibase[(size_t)t * GATES + xrow];

        if (k > 0) {
            int tprev = dir ? (t + 1) : (t - 1);
            if (tid < HID) {
                const unsigned want = tagbase + (unsigned)k;
                size_t eidx = (size_t)tprev * E1 + dirHID + tid;
                const volatile unsigned long long* p =
                    (const volatile unsigned long long*)&hx[eidx];
                unsigned long long w;
                int spin = 0;
                for (;;) {
                    w = *p;                               // proven MALL exchange
                    if ((unsigned)(w >> 32) == want) break;
                    if (++spin >= 24) {                   // agent-scope fallback
                        w = __hip_atomic_load(&hx2[eidx], __ATOMIC_RELAXED,
                                              __HIP_MEMORY_SCOPE_AGENT);
                        if ((unsigned)(w >> 32) == want) break;
                        spin = 0;
                    }
                }
                hbuf[hIdx] = __uint_as_float((unsigned)w);
            }
        } else {
            if (tid < HID) hbuf[hIdx] = 0.f;
        }
        __syncthreads();                                   // B1

        // ---- dot: 2 rows x 25 cols per lane; h broadcast from LDS via b128
        const float* hb = &hbuf[chunk * 28];
        float4 h4a = *(const float4*)(hb + 0);
        float4 h4b = *(const float4*)(hb + 4);
        float4 h4c = *(const float4*)(hb + 8);
        float4 h4d = *(const float4*)(hb + 12);
        float4 h4e = *(const float4*)(hb + 16);
        float4 h4f = *(const float4*)(hb + 20);
        float hv[25] = {h4a.x, h4a.y, h4a.z, h4a.w, h4b.x, h4b.y, h4b.z, h4b.w,
                        h4c.x, h4c.y, h4c.z, h4c.w, h4d.x, h4d.y, h4d.z, h4d.w,
                        h4e.x, h4e.y, h4e.z, h4e.w, h4f.x, h4f.y, h4f.z, h4f.w,
                        hb[24]};
        float acc0 = 0.f, acc1 = 0.f;
#pragma unroll
        for (int c = 0; c < 25; ++c) {
            acc0 = fmaf(wv[0][c], hv[c], acc0);
            acc1 = fmaf(wv[1][c], hv[c], acc1);
        }
        partials[rg * 2 + 0][chunk] = acc0;
        partials[rg * 2 + 1][chunk] = acc1;
        __syncthreads();                                   // B2

        // ---- reduce 16 column-chunks per gate row, add xi (same order as before)
        if (tid < ROWS) {
            const float4* pr = (const float4*)&partials[tid][0];
            float4 p0 = pr[0], p1 = pr[1], p2 = pr[2], p3 = pr[3];
            float s = p0.x + p0.y + p0.z + p0.w
                    + p1.x + p1.y + p1.z + p1.w
                    + p2.x + p2.y + p2.z + p2.w
                    + p3.x + p3.y + p3.z + p3.w;
            gates[tid] = s + xiv;
        }
        __syncthreads();                                   // B3

        // ---- nonlinearity + state update + tagged publish (wave-7 lanes:
        //      non-polling, so their MALL store-acks drain off the critical path)
        if (pl >= 0 && pl < HSL) {
            float4 g4 = *(const float4*)&gates[pl * 4];    // (i,f,g,o)
            float ig = sigm(g4.x), fg = sigm(g4.y), cg = tanh_f(g4.z), og = sigm(g4.w);
            cstate = fg * cstate + ig * cg;
            float hv2 = og * tanh_f(cstate);
            unsigned long long w =
                ((unsigned long long)(tagbase + (unsigned)k + 1u) << 32) |
                (unsigned long long)(unsigned)__float_as_uint(hv2);
            size_t eidx = (size_t)t * E1 + myelem;
            *(volatile unsigned long long*)&hx[eidx] = w;          // proven path
            __hip_atomic_store(&hx2[eidx], w, __ATOMIC_RELAXED,
                               __HIP_MEMORY_SCOPE_AGENT);          // MALL backup
        }
        // no trailing barrier: next iteration's barriers protect LDS reuse
    }
}

// ------------------------------------------------------------- final scores
__global__ void scores_kernel(const float* __restrict__ sv, const float* __restrict__ tv,
                              const void* __restrict__ fb, void* __restrict__ out,
                              const unsigned* __restrict__ dtf) {
    int idx = blockIdx.x * blockDim.x + threadIdx.x;   // < SEQ*SEQ
    int i = idx >> 9, j = idx & 511;
    int isbf = (int)*dtf;
    float v = tanh_f(sv[i] + tv[j] + loadx(fb, 0, isbf));
    if (isbf) ((unsigned short*)out)[idx] = f2bf(v);
    else      ((float*)out)[idx] = v;
}

// ---------------------------------------------------------------- workspace
static constexpr size_t OFF_X    = 0;          // 512*400*4    =   819,200
static constexpr size_t OFF_XI   = 819200;     // 2*512*1600*4 = 6,553,600
static constexpr size_t OFF_SV   = 7372800;    // 2048
static constexpr size_t OFF_TV   = 7374848;    // 2048
static constexpr size_t OFF_DTF  = 7376896;    // 64
static constexpr size_t OFF_SYNC = 7376960;    // 2 * 64 (formation areas)
static constexpr size_t OFF_HX   = 7377216;    // 512*800*8 = 3,276,800
static constexpr size_t OFF_HX2  = 10654016;   // 512*800*8 = 3,276,800 (ends 13.93 MB)

extern "C" void kernel_launch(void* const* d_in, const int* in_sizes, int n_in,
                              void* d_out, int out_size, void* d_ws, size_t ws_size,
                              hipStream_t stream) {
    const int* words = (const int*)d_in[0];
    const int* tags  = (const int*)d_in[1];
    const void* wemb = d_in[3];
    const void* temb = d_in[4];
    const void* wih0 = d_in[5];
    const void* whh0 = d_in[6];
    const void* bih0 = d_in[7];
    const void* bhh0 = d_in[8];
    const void* wih1 = d_in[9];
    const void* whh1 = d_in[10];
    const void* bih1 = d_in[11];
    const void* bhh1 = d_in[12];
    const void* fw   = d_in[13];
    const void* fb   = d_in[14];

    char* ws = (char*)d_ws;
    float* x               = (float*)(ws + OFF_X);
    float* xi              = (float*)(ws + OFF_XI);
    float* sv              = (float*)(ws + OFF_SV);
    float* tv              = (float*)(ws + OFF_TV);
    unsigned* dtf          = (unsigned*)(ws + OFF_DTF);
    SyncArea* sync0        = (SyncArea*)(ws + OFF_SYNC);
    SyncArea* sync1        = (SyncArea*)(ws + OFF_SYNC + 64);
    unsigned long long* hx  = (unsigned long long*)(ws + OFF_HX);
    unsigned long long* hx2 = (unsigned long long*)(ws + OFF_HX2);

    // embed fuses dtype detection + sync-area zeroing (ws re-poisoned 0xAA)
    embed_kernel<<<SEQ, 128, 0, stream>>>(words, tags, wemb, temb, x, dtf,
                                          (unsigned*)(ws + OFF_SYNC));

    // layer 0 (tags 1..512); rec0's unclaimed WGs compute layer-1's xi in place
    proj_kernel<<<dim3(4, 25, 2), 256, 0, stream>>>(x, 0, wih0, bih0, bhh0, xi, HID, dtf);
    rec_kernel<<<RECGRID, 512, 0, stream>>>(xi, whh0, hx, hx2, 0u, sync0, dtf,
                                            0, wih1, bih1, bhh1, xi,
                                            nullptr, nullptr, nullptr);

    // layer 1 (tags 513..1024); rec1's unclaimed WGs compute sv/tv
    rec_kernel<<<RECGRID, 512, 0, stream>>>(xi, whh1, hx, hx2, 512u, sync1, dtf,
                                            1, nullptr, nullptr, nullptr, nullptr,
                                            fw, sv, tv);

    // pairwise scores
    scores_kernel<<<(SEQ * SEQ) / 256, 256, 0, stream>>>(sv, tv, fb, d_out, dtf);
}

// Round 10
// 1688.832 us; speedup vs baseline: 1.0099x; 1.0099x over previous
//
#include <hip/hip_runtime.h>

// Problem constants
#define SEQ 512
#define HID 400
#define GATES 1600   // 4*HID
#define E1 800       // 2*HID
#define TEAM 25      // workgroups per direction in the recurrence
#define RECGRID 256  // candidate WGs launched for team formation (32/XCD)
#define ROWS 64      // gate rows per WG   = GATES/TEAM
#define HSL 16       // h values per WG    = HID/TEAM

__device__ __forceinline__ float bf2f(unsigned short u) {
    return __uint_as_float(((unsigned)u) << 16);
}
__device__ __forceinline__ unsigned short f2bf(float f) {
    unsigned u = __float_as_uint(f);
    u += 0x7FFFu + ((u >> 16) & 1u);   // RNE
    return (unsigned short)(u >> 16);
}
__device__ __forceinline__ float sigm(float x) { return 1.f / (1.f + __expf(-x)); }
__device__ __forceinline__ float tanh_f(float x) {
    float xc = fminf(fmaxf(x, -15.f), 15.f);
    float e = __expf(2.f * xc);
    return (e - 1.f) / (e + 1.f);
}
__device__ __forceinline__ float loadx(const void* p, size_t i, int isbf) {
    return isbf ? bf2f(((const unsigned short*)p)[i]) : ((const float*)p)[i];
}

// R1-style tag poll with hedge: proven MALL exchange loop (do not restructure;
// R2/R4/R6/R7 all showed any variation regresses).
__device__ __forceinline__ unsigned long long poll_tag(
        const unsigned long long* hx, const unsigned long long* hx2,
        size_t eidx, unsigned want) {
    const volatile unsigned long long* p =
        (const volatile unsigned long long*)&hx[eidx];
    unsigned long long w;
    int spin = 0;
    for (;;) {
        w = *p;
        if ((unsigned)(w >> 32) == want) break;
        if (++spin >= 24) {
            w = __hip_atomic_load(&hx2[eidx], __ATOMIC_RELAXED,
                                  __HIP_MEMORY_SCOPE_AGENT);
            if ((unsigned)(w >> 32) == want) break;
            spin = 0;
        }
    }
    return w;
}

// ------------------------------------------------- embedding (+fused detect)
__global__ void embed_kernel(const int* __restrict__ words, const int* __restrict__ tags,
                             const void* __restrict__ wemb, const void* __restrict__ temb,
                             float* __restrict__ x /* [SEQ][400] f32 */,
                             unsigned* __restrict__ dtf,
                             unsigned* __restrict__ syncz /* 128B to zero */) {
    __shared__ int cnt;
    int tid = threadIdx.x;                 // 128 threads
    int t = blockIdx.x;
    if (tid == 0) cnt = 0;
    __syncthreads();
    const unsigned short* wh = (const unsigned short*)wemb;
    int pass = 0;
    for (int i = 0; i < 16; ++i) {         // 128*16 = same 2048-sample set
        unsigned short u = wh[tid * 16 + i];
        int e = (u >> 7) & 0xFF;
        pass += (e >= 100 && e <= 130) ? 1 : 0;
    }
    atomicAdd(&cnt, pass);
    __syncthreads();
    int isbf = (cnt >= 1843) ? 1 : 0;      // 90% of 2048
    if (t == 0) {
        if (tid < 32) syncz[tid] = 0u;
        if (tid == 0) *dtf = (unsigned)isbf;
    }
    int w = words[t], g = tags[t];
    for (int k = tid; k < HID; k += blockDim.x) {
        float v = (k < 300) ? loadx(wemb, (size_t)w * 300 + k, isbf)
                            : loadx(temb, (size_t)g * 100 + (k - 300), isbf);
        x[(size_t)t * HID + k] = v;
    }
}

// ---------------------------------------------------------- input projection
// (layer 0 only; layer 1's projection runs as helper work inside rec0).
__global__ __launch_bounds__(256) void proj_kernel(
        const void* __restrict__ Araw, int tagged,
        const void* __restrict__ Wraw /* [2][GATES][K] */,
        const void* __restrict__ bihRaw, const void* __restrict__ bhhRaw,
        float* __restrict__ xi /* [2][SEQ][GATES] */,
        int K, const unsigned* __restrict__ dtf) {
    const int isbf = (int)*dtf;
    __shared__ float As[16][132];
    __shared__ float Ws[16][68];
    int tid = threadIdx.x;
    int t0 = blockIdx.x * 128, n0 = blockIdx.y * 64, dir = blockIdx.z;
    int arow = tid >> 1, akoff = (tid & 1) * 8;
    int wrow = tid >> 2, wkoff = (tid & 3) * 4;
    int tx = (tid & 15) * 4;        // n-offset 0..63
    int ty = (tid >> 4) * 8;        // t-offset 0..127

    const float* Af = (const float*)Araw + (size_t)(t0 + arow) * K + akoff;
    const unsigned long long* At = (const unsigned long long*)Araw +
                                   (size_t)(t0 + arow) * K + akoff;
    size_t wbase = (size_t)(dir * GATES + n0 + wrow) * K + wkoff;
    const float* Wf = (const float*)Wraw + wbase;
    const unsigned short* Wh = (const unsigned short*)Wraw + wbase;

    float acc[8][4] = {};
    for (int k0 = 0; k0 < K; k0 += 16) {
        float av8[8];
        if (tagged) {
            ulonglong2 q0 = *(const ulonglong2*)(At + k0);
            ulonglong2 q1 = *(const ulonglong2*)(At + k0 + 2);
            ulonglong2 q2 = *(const ulonglong2*)(At + k0 + 4);
            ulonglong2 q3 = *(const ulonglong2*)(At + k0 + 6);
            av8[0] = __uint_as_float((unsigned)q0.x); av8[1] = __uint_as_float((unsigned)q0.y);
            av8[2] = __uint_as_float((unsigned)q1.x); av8[3] = __uint_as_float((unsigned)q1.y);
            av8[4] = __uint_as_float((unsigned)q2.x); av8[5] = __uint_as_float((unsigned)q2.y);
            av8[6] = __uint_as_float((unsigned)q3.x); av8[7] = __uint_as_float((unsigned)q3.y);
        } else {
            float4 a0 = *(const float4*)(Af + k0);
            float4 a1 = *(const float4*)(Af + k0 + 4);
            av8[0] = a0.x; av8[1] = a0.y; av8[2] = a0.z; av8[3] = a0.w;
            av8[4] = a1.x; av8[5] = a1.y; av8[6] = a1.z; av8[7] = a1.w;
        }
        float4 wv;
        if (isbf) {
            ushort4 w4 = *(const ushort4*)(Wh + k0);
            wv = make_float4(bf2f(w4.x), bf2f(w4.y), bf2f(w4.z), bf2f(w4.w));
        } else {
            wv = *(const float4*)(Wf + k0);
        }
        __syncthreads();
#pragma unroll
        for (int i = 0; i < 8; ++i) As[akoff + i][arow] = av8[i];
        Ws[wkoff + 0][wrow] = wv.x; Ws[wkoff + 1][wrow] = wv.y;
        Ws[wkoff + 2][wrow] = wv.z; Ws[wkoff + 3][wrow] = wv.w;
        __syncthreads();
#pragma unroll
        for (int kk = 0; kk < 16; ++kk) {
            float4 alo = *(const float4*)&As[kk][ty];
            float4 ahi = *(const float4*)&As[kk][ty + 4];
            float4 w4  = *(const float4*)&Ws[kk][tx];
            float av[8] = {alo.x, alo.y, alo.z, alo.w, ahi.x, ahi.y, ahi.z, ahi.w};
            float wvv[4] = {w4.x, w4.y, w4.z, w4.w};
#pragma unroll
            for (int i = 0; i < 8; ++i)
#pragma unroll
                for (int j = 0; j < 4; ++j)
                    acc[i][j] = fmaf(av[i], wvv[j], acc[i][j]);
        }
    }
    float bias[4];
#pragma unroll
    for (int j = 0; j < 4; ++j) {
        int n = n0 + tx + j;
        bias[j] = loadx(bihRaw, dir * GATES + n, isbf) + loadx(bhhRaw, dir * GATES + n, isbf);
    }
    float* xout = xi + (size_t)dir * SEQ * GATES;
#pragma unroll
    for (int i = 0; i < 8; ++i) {
        int t = t0 + ty + i;
        float4 o = make_float4(acc[i][0] + bias[0], acc[i][1] + bias[1],
                               acc[i][2] + bias[2], acc[i][3] + bias[3]);
        *(float4*)&xout[(size_t)t * GATES + n0 + tx] = o;
    }
}

// ------------------------------------------------------------- LSTM recurrence
// ROUND-14. R9 post-mortem: dispatch fusion worked (absmax unchanged, races
// none) but helper PER-ELEMENT VOLATILE poll loads tripled FETCH (9.7->32MB)
// and the MALL congestion slowed the rec teams 706->806us. Fix: helper data
// reads become CACHED loads + tag-check + poll_tag fallback. The tag rides in
// the same u64 as the data, so a normal ulonglong2 load self-verifies; only
// unpublished/stale elements (boundary rows) fall back to the volatile path.
// Cached reads L2-hit across the 25 n0-tiles sharing a t0 -> helper MALL
// traffic drops ~50x. False-match safety: any line with tag==want holds the
// correct value (tags unique per layer within a run; deterministic reruns
// make prior-run layer-matched lines bitwise identical; R9 validated the
// cross-dispatch visibility path). Rec-team path: frozen R5, byte-identical.
struct SyncArea { unsigned cnt[8]; unsigned claim[2]; unsigned pad[6]; };

__global__ __launch_bounds__(512, 2) void rec_kernel(
        const float* __restrict__ xi /* [2][SEQ][GATES] */,
        const void* __restrict__ whhRaw /* [2][GATES][HID] */,
        unsigned long long* __restrict__ hx  /* [SEQ][E1] tagged, volatile path */,
        unsigned long long* __restrict__ hx2 /* [SEQ][E1] tagged, MALL backup */,
        unsigned tagbase, SyncArea* __restrict__ sy,
        const unsigned* __restrict__ dtf,
        int mode,
        const void* __restrict__ wih1, const void* __restrict__ bih1,
        const void* __restrict__ bhh1, float* __restrict__ xiOut,
        const void* __restrict__ fw, float* __restrict__ sv,
        float* __restrict__ tv) {
    int tid = threadIdx.x;
    __shared__ int role[2];   // [0]=dir (0/1/2=helper), [1]=wg rank
    if (tid == 0) {
        unsigned xcd = __builtin_amdgcn_s_getreg((3 << 11) | 20) & 0xFu; // HW_REG_XCC_ID
        unsigned rank = atomicAdd(&sy->cnt[xcd], 1u);
        unsigned group = rank / TEAM;
        unsigned key = 1u + xcd * 64u + group;
        if ((rank % TEAM) == TEAM - 1) {          // group leader: claim a direction
            unsigned prev = atomicCAS(&sy->claim[0], 0u, key);
            if (prev != 0u) atomicCAS(&sy->claim[1], 0u, key);
        }
        int dir = -1;
        while (dir < 0) {
            unsigned c0 = __hip_atomic_load(&sy->claim[0], __ATOMIC_RELAXED,
                                            __HIP_MEMORY_SCOPE_AGENT);
            unsigned c1 = __hip_atomic_load(&sy->claim[1], __ATOMIC_RELAXED,
                                            __HIP_MEMORY_SCOPE_AGENT);
            if (c0 == key) dir = 0;
            else if (c1 == key) dir = 1;
            else if (c0 != 0u && c1 != 0u) dir = 2;
        }
        role[0] = dir;
        role[1] = (int)(rank % TEAM);
    }
    __syncthreads();
    const int dir = role[0];
    const int wg  = role[1];

    __shared__ __align__(16) float hbuf[16 * 28];        // stride-28 padded
    __shared__ __align__(16) float partials[ROWS][20];   // 16 cols used, 20 for align
    __shared__ __align__(16) float gates[ROWS];
    // helper-only staging
    __shared__ __align__(16) float As2[16][132];
    __shared__ __align__(16) float Ws2[16][68];
    __shared__ int hticket;

    if (dir == 2) {
        // ======================= HELPER PATH (unclaimed WGs) =================
        const int isbf = (int)*dtf;
        if (mode == 0) {
            // ---- layer-1 input projection: 200 tiles of 128x64
            for (;;) {
                if (tid == 0) hticket = (int)atomicAdd(&sy->pad[0], 1u);
                __syncthreads();
                int tk = hticket;
                if (tk >= 200) return;
                int t0 = (tk & 3) * 128;
                int n0 = ((tk >> 2) % 25) * 64;
                int dw = tk / 100;
                // sentinels: fwd row t0+127 (tag t0+128), bwd row t0 (tag 512-t0)
                if (tid == 0)
                    (void)poll_tag(hx, hx2, (size_t)(t0 + 127) * E1 + 0,
                                   (unsigned)(t0 + 128));
                if (tid == 1)
                    (void)poll_tag(hx, hx2, (size_t)t0 * E1 + HID,
                                   (unsigned)(512 - t0));
                __syncthreads();

                float acc[4][4] = {};
                int arow = tid >> 2, akoff = (tid & 3) * 4;   // A stage: 4 elems
                int wrow = tid >> 3, wkoff = (tid & 7) * 2;   // W stage: 2 elems
                int tx = (tid & 15) * 4, ty = (tid >> 4) * 4; // 4x4 micro-acc
                int tA = t0 + arow;
                const unsigned long long* hrow = hx + (size_t)tA * E1;
                for (int k0 = 0; k0 < E1; k0 += 16) {
                    int e0 = k0 + akoff;
                    // 400 % 16 == 0 -> a 4-elem group never crosses the
                    // fwd/bwd boundary; one tag for all 4
                    unsigned want = (e0 < HID) ? (unsigned)(tA + 1)
                                               : (unsigned)(512 - tA);
                    // CACHED load + self-verify (tag in the same u64);
                    // fallback to the proven volatile poll only on mismatch
                    ulonglong2 q0 = *(const ulonglong2*)(hrow + e0);
                    ulonglong2 q1 = *(const ulonglong2*)(hrow + e0 + 2);
                    unsigned long long qq[4] = {q0.x, q0.y, q1.x, q1.y};
                    float a4[4];
#pragma unroll
                    for (int j = 0; j < 4; ++j) {
                        if ((unsigned)(qq[j] >> 32) != want)
                            qq[j] = poll_tag(hx, hx2, (size_t)tA * E1 + e0 + j, want);
                        a4[j] = __uint_as_float((unsigned)qq[j]);
                    }
                    float wf0 = loadx(wih1, ((size_t)(dw * GATES + n0 + wrow)) * E1
                                            + k0 + wkoff + 0, isbf);
                    float wf1 = loadx(wih1, ((size_t)(dw * GATES + n0 + wrow)) * E1
                                            + k0 + wkoff + 1, isbf);
                    __syncthreads();
#pragma unroll
                    for (int j = 0; j < 4; ++j) As2[akoff + j][arow] = a4[j];
                    Ws2[wkoff + 0][wrow] = wf0;
                    Ws2[wkoff + 1][wrow] = wf1;
                    __syncthreads();
#pragma unroll
                    for (int kk = 0; kk < 16; ++kk) {
                        float4 av = *(const float4*)&As2[kk][ty];
                        float4 w4 = *(const float4*)&Ws2[kk][tx];
                        float avv[4] = {av.x, av.y, av.z, av.w};
                        float wvv[4] = {w4.x, w4.y, w4.z, w4.w};
#pragma unroll
                        for (int i = 0; i < 4; ++i)
#pragma unroll
                            for (int j = 0; j < 4; ++j)
                                acc[i][j] = fmaf(avv[i], wvv[j], acc[i][j]);
                    }
                }
                float bias[4];
#pragma unroll
                for (int j = 0; j < 4; ++j) {
                    int n = n0 + tx + j;
                    bias[j] = loadx(bih1, dw * GATES + n, isbf)
                            + loadx(bhh1, dw * GATES + n, isbf);
                }
                float* xo = xiOut + (size_t)dw * SEQ * GATES;
#pragma unroll
                for (int i = 0; i < 4; ++i) {
                    int t = t0 + ty + i;
                    float4 o = make_float4(acc[i][0] + bias[0], acc[i][1] + bias[1],
                                           acc[i][2] + bias[2], acc[i][3] + bias[3]);
                    *(float4*)&xo[(size_t)t * GATES + n0 + tx] = o;
                }
                __syncthreads();   // protect LDS before next ticket
            }
        } else {
            // ---- st: 64 chunks x 8 rows, one row per wave, exact st order
            int wid = tid >> 6, lane = tid & 63;
            for (;;) {
                if (tid == 0) hticket = (int)atomicAdd(&sy->pad[0], 1u);
                __syncthreads();
                int ck = hticket;
                if (ck >= 64) return;
                int i = ck * 8 + wid;
                // sentinels for row i (layer-1 tags: fwd 513+i, bwd 1024-i)
                if (lane == 0) {
                    (void)poll_tag(hx, hx2, (size_t)i * E1 + 0, (unsigned)(513 + i));
                    (void)poll_tag(hx, hx2, (size_t)i * E1 + HID, (unsigned)(1024 - i));
                }
                float s = 0.f, t2 = 0.f;
                for (int j = lane; j < E1; j += 64) {
                    unsigned want = (j < HID) ? (unsigned)(513 + i)
                                              : (unsigned)(1024 - i);
                    unsigned long long w = hx[(size_t)i * E1 + j];   // cached
                    if ((unsigned)(w >> 32) != want)
                        w = poll_tag(hx, hx2, (size_t)i * E1 + j, want);
                    float hv = __uint_as_float((unsigned)w);
                    s  += hv * loadx(fw, j, isbf);
                    t2 += hv * loadx(fw, E1 + j, isbf);
                }
#pragma unroll
                for (int o = 32; o > 0; o >>= 1) {
                    s  += __shfl_xor(s, o, 64);
                    t2 += __shfl_xor(t2, o, 64);
                }
                if (lane == 0) { sv[i] = s; tv[i] = t2; }
                __syncthreads();   // rejoin waves before next ticket
            }
        }
    }
    // ========================== REC-TEAM PATH (frozen R5) ====================
    const int chunk = tid & 15;    // 0..15 -> cols chunk*25..+24
    const int rg    = tid >> 4;    // 0..31 -> rows rg*2..+1
    const int isbf  = (int)*dtf;
    const int dirHID = dir * HID;

    // ---- load this lane's weight tile: 2 rows x 25 cols, REGISTER-resident
    float wv[2][25];
#pragma unroll
    for (int r = 0; r < 2; ++r) {
        int lr = rg * 2 + r;                // local row 0..63
        int jj = lr >> 2, gg = lr & 3;      // h index, gate (i,f,g,o)
        int grow = gg * HID + wg * HSL + jj; // global gate row
        size_t base = ((size_t)dir * GATES + grow) * HID + chunk * 25;
        if (isbf) {
            const unsigned short* p = (const unsigned short*)whhRaw + base;
#pragma unroll
            for (int c = 0; c < 25; ++c) wv[r][c] = bf2f(p[c]);
        } else {
            const float* p = (const float*)whhRaw + base;
#pragma unroll
            for (int c = 0; c < 25; ++c) wv[r][c] = p[c];
        }
    }

    int xrow = 0;
    if (tid < ROWS) { int jj = tid >> 2, gg = tid & 3; xrow = gg * HID + wg * HSL + jj; }
    const int hIdx = (tid / 25) * 28 + (tid % 25);   // padded scatter slot (tid<HID)
    const float* xibase = xi + (size_t)dir * SEQ * GATES;
    // wave-7 publisher lanes (tid 448..463): they never poll (poll set tid<400)
    const int pl = tid - 448;                // publisher lane 0..15 when valid
    float cstate = 0.f;                      // lane pl<16 owns c for h-idx wg*HSL+pl
    size_t myelem = dirHID + wg * HSL + (pl & 15);

#pragma unroll 1
    for (int k = 0; k < SEQ; ++k) {
        int t = dir ? (SEQ - 1 - k) : k;
        float xiv = 0.f;
        if (tid < ROWS) xiv = xibase[(size_t)t * GATES + xrow];

        if (k > 0) {
            int tprev = dir ? (t + 1) : (t - 1);
            if (tid < HID) {
                const unsigned want = tagbase + (unsigned)k;
                size_t eidx = (size_t)tprev * E1 + dirHID + tid;
                const volatile unsigned long long* p =
                    (const volatile unsigned long long*)&hx[eidx];
                unsigned long long w;
                int spin = 0;
                for (;;) {
                    w = *p;                               // proven MALL exchange
                    if ((unsigned)(w >> 32) == want) break;
                    if (++spin >= 24) {                   // agent-scope fallback
                        w = __hip_atomic_load(&hx2[eidx], __ATOMIC_RELAXED,
                                              __HIP_MEMORY_SCOPE_AGENT);
                        if ((unsigned)(w >> 32) == want) break;
                        spin = 0;
                    }
                }
                hbuf[hIdx] = __uint_as_float((unsigned)w);
            }
        } else {
            if (tid < HID) hbuf[hIdx] = 0.f;
        }
        __syncthreads();                                   // B1

        // ---- dot: 2 rows x 25 cols per lane; h broadcast from LDS via b128
        const float* hb = &hbuf[chunk * 28];
        float4 h4a = *(const float4*)(hb + 0);
        float4 h4b = *(const float4*)(hb + 4);
        float4 h4c = *(const float4*)(hb + 8);
        float4 h4d = *(const float4*)(hb + 12);
        float4 h4e = *(const float4*)(hb + 16);
        float4 h4f = *(const float4*)(hb + 20);
        float hv[25] = {h4a.x, h4a.y, h4a.z, h4a.w, h4b.x, h4b.y, h4b.z, h4b.w,
                        h4c.x, h4c.y, h4c.z, h4c.w, h4d.x, h4d.y, h4d.z, h4d.w,
                        h4e.x, h4e.y, h4e.z, h4e.w, h4f.x, h4f.y, h4f.z, h4f.w,
                        hb[24]};
        float acc0 = 0.f, acc1 = 0.f;
#pragma unroll
        for (int c = 0; c < 25; ++c) {
            acc0 = fmaf(wv[0][c], hv[c], acc0);
            acc1 = fmaf(wv[1][c], hv[c], acc1);
        }
        partials[rg * 2 + 0][chunk] = acc0;
        partials[rg * 2 + 1][chunk] = acc1;
        __syncthreads();                                   // B2

        // ---- reduce 16 column-chunks per gate row, add xi (same order as before)
        if (tid < ROWS) {
            const float4* pr = (const float4*)&partials[tid][0];
            float4 p0 = pr[0], p1 = pr[1], p2 = pr[2], p3 = pr[3];
            float s = p0.x + p0.y + p0.z + p0.w
                    + p1.x + p1.y + p1.z + p1.w
                    + p2.x + p2.y + p2.z + p2.w
                    + p3.x + p3.y + p3.z + p3.w;
            gates[tid] = s + xiv;
        }
        __syncthreads();                                   // B3

        // ---- nonlinearity + state update + tagged publish (wave-7 lanes:
        //      non-polling, so their MALL store-acks drain off the critical path)
        if (pl >= 0 && pl < HSL) {
            float4 g4 = *(const float4*)&gates[pl * 4];    // (i,f,g,o)
            float ig = sigm(g4.x), fg = sigm(g4.y), cg = tanh_f(g4.z), og = sigm(g4.w);
            cstate = fg * cstate + ig * cg;
            float hv2 = og * tanh_f(cstate);
            unsigned long long w =
                ((unsigned long long)(tagbase + (unsigned)k + 1u) << 32) |
                (unsigned long long)(unsigned)__float_as_uint(hv2);
            size_t eidx = (size_t)t * E1 + myelem;
            *(volatile unsigned long long*)&hx[eidx] = w;          // proven path
            __hip_atomic_store(&hx2[eidx], w, __ATOMIC_RELAXED,
                               __HIP_MEMORY_SCOPE_AGENT);          // MALL backup
        }
        // no trailing barrier: next iteration's barriers protect LDS reuse
    }
}

// ------------------------------------------------------------- final scores
__global__ void scores_kernel(const float* __restrict__ sv, const float* __restrict__ tv,
                              const void* __restrict__ fb, void* __restrict__ out,
                              const unsigned* __restrict__ dtf) {
    int idx = blockIdx.x * blockDim.x + threadIdx.x;   // < SEQ*SEQ
    int i = idx >> 9, j = idx & 511;
    int isbf = (int)*dtf;
    float v = tanh_f(sv[i] + tv[j] + loadx(fb, 0, isbf));
    if (isbf) ((unsigned short*)out)[idx] = f2bf(v);
    else      ((float*)out)[idx] = v;
}

// ---------------------------------------------------------------- workspace
static constexpr size_t OFF_X    = 0;          // 512*400*4    =   819,200
static constexpr size_t OFF_XI   = 819200;     // 2*512*1600*4 = 6,553,600
static constexpr size_t OFF_SV   = 7372800;    // 2048
static constexpr size_t OFF_TV   = 7374848;    // 2048
static constexpr size_t OFF_DTF  = 7376896;    // 64
static constexpr size_t OFF_SYNC = 7376960;    // 2 * 64 (formation areas)
static constexpr size_t OFF_HX   = 7377216;    // 512*800*8 = 3,276,800
static constexpr size_t OFF_HX2  = 10654016;   // 512*800*8 = 3,276,800 (ends 13.93 MB)

extern "C" void kernel_launch(void* const* d_in, const int* in_sizes, int n_in,
                              void* d_out, int out_size, void* d_ws, size_t ws_size,
                              hipStream_t stream) {
    const int* words = (const int*)d_in[0];
    const int* tags  = (const int*)d_in[1];
    const void* wemb = d_in[3];
    const void* temb = d_in[4];
    const void* wih0 = d_in[5];
    const void* whh0 = d_in[6];
    const void* bih0 = d_in[7];
    const void* bhh0 = d_in[8];
    const void* wih1 = d_in[9];
    const void* whh1 = d_in[10];
    const void* bih1 = d_in[11];
    const void* bhh1 = d_in[12];
    const void* fw   = d_in[13];
    const void* fb   = d_in[14];

    char* ws = (char*)d_ws;
    float* x               = (float*)(ws + OFF_X);
    float* xi              = (float*)(ws + OFF_XI);
    float* sv              = (float*)(ws + OFF_SV);
    float* tv              = (float*)(ws + OFF_TV);
    unsigned* dtf          = (unsigned*)(ws + OFF_DTF);
    SyncArea* sync0        = (SyncArea*)(ws + OFF_SYNC);
    SyncArea* sync1        = (SyncArea*)(ws + OFF_SYNC + 64);
    unsigned long long* hx  = (unsigned long long*)(ws + OFF_HX);
    unsigned long long* hx2 = (unsigned long long*)(ws + OFF_HX2);

    // embed fuses dtype detection + sync-area zeroing (ws re-poisoned 0xAA)
    embed_kernel<<<SEQ, 128, 0, stream>>>(words, tags, wemb, temb, x, dtf,
                                          (unsigned*)(ws + OFF_SYNC));

    // layer 0 (tags 1..512); rec0's unclaimed WGs compute layer-1's xi in place
    proj_kernel<<<dim3(4, 25, 2), 256, 0, stream>>>(x, 0, wih0, bih0, bhh0, xi, HID, dtf);
    rec_kernel<<<RECGRID, 512, 0, stream>>>(xi, whh0, hx, hx2, 0u, sync0, dtf,
                                            0, wih1, bih1, bhh1, xi,
                                            nullptr, nullptr, nullptr);

    // layer 1 (tags 513..1024); rec1's unclaimed WGs compute sv/tv
    rec_kernel<<<RECGRID, 512, 0, stream>>>(xi, whh1, hx, hx2, 512u, sync1, dtf,
                                            1, nullptr, nullptr, nullptr, nullptr,
                                            fw, sv, tv);

    // pairwise scores
    scores_kernel<<<(SEQ * SEQ) / 256, 256, 0, stream>>>(sv, tv, fb, d_out, dtf);
}